// Round 12
// baseline (27.787 us; speedup 1.0000x reference)
//
#include <hip/hip_runtime.h>

// Problem constants (match reference)
constexpr int B_IMG = 8;
constexpr int A_ANCH = 150000;
constexpr int C_CLS = 10;
constexpr int TPB = 256;
constexpr int BA = TPB * 2;                       // 512 anchors per block
constexpr int NBX = (A_ANCH + BA - 1) / BA;       // 293
constexpr int F4_PER_IMG = A_ANCH * C_CLS / 4;    // 375000
constexpr int F4_PER_BLK = BA * C_CLS / 4;        // 1280

// ws layout: float att_part[B][NBX], rl_part[B][NBX], np_part[B][NBX]
//
// Clean coalescing test (3rd attempt; R4 poisoned by scatter, R10 by LDS byte
// bank conflicts):
//   Phase A: thread owns anchors blk*512+tid, +256 (lane-consecutive anchor
//            float4 loads) -> IoU -> FLOAT flag (0/1/2) in LDS + regression.
//   Phase B: 5 lane-consecutive attr float4s/thread (perfect coalescing);
//            flags read as floats (consecutive words -> <=2-way bank alias,
//            free) 2 reads per float4; branchless gated focal term.
__global__ __launch_bounds__(TPB) void focal_main(
    const float* __restrict__ attr,   // (B, A, C)
    const float* __restrict__ regr,   // (B, A, 4)
    const float* __restrict__ anch,   // (A, 4)
    const float* __restrict__ ann,    // (B, 14)
    float* __restrict__ att_part,
    float* __restrict__ rl_part,
    float* __restrict__ np_part)
{
    __shared__ float sF[BA];   // 0.0 = ignore, 1.0 = neg, 2.0 = pos

    const int b   = blockIdx.y;
    const int blk = blockIdx.x;
    const int tid = threadIdx.x;

    // ---- issue ALL coalesced global loads upfront ----
    const float4* atp = reinterpret_cast<const float4*>(attr) + (size_t)b * F4_PER_IMG;
    float4 av[5];
#pragma unroll
    for (int j = 0; j < 5; ++j) {
        int f4 = blk * F4_PER_BLK + j * TPB + tid;
        f4 = (f4 < F4_PER_IMG) ? f4 : (F4_PER_IMG - 1);   // clamp addr only; flags gate
        av[j] = atp[f4];
    }
    const int A0 = blk * BA + tid;
    const int A1 = A0 + TPB;
    const bool v0 = (A0 < A_ANCH);
    const bool v1 = (A1 < A_ANCH);
    const float4* anp = reinterpret_cast<const float4*>(anch);
    const float4 an0 = anp[v0 ? A0 : 0];
    const float4 an1 = anp[v1 ? A1 : 0];

    // annotation (wave-uniform scalar loads)
    const float* annb = ann + b * 14;
    const float bx0 = annb[0], by0 = annb[1], bx1 = annb[2], by1 = annb[3];
    unsigned labmask = 0;
#pragma unroll
    for (int c = 0; c < C_CLS; ++c) labmask |= (annb[4 + c] == 1.0f ? 1u : 0u) << c;

    const float gw_raw = bx1 - bx0;
    const float gh_raw = by1 - by0;
    const float area = gw_raw * gh_raw;
    const float gcx = bx0 + 0.5f * gw_raw;
    const float gcy = by0 + 0.5f * gh_raw;
    const float gw = fmaxf(gw_raw, 1.0f);
    const float gh = fmaxf(gh_raw, 1.0f);

    const float TH  = (float)(1.0 / 9.0);
    const float SUB = (float)(0.5 / 9.0);
    const float PHI = (float)(1.0 - 0.0001);

    float att_sum = 0.0f;
    float rl_sum = 0.0f;
    float npf = 0.0f;

    // ---- Phase A: flags + regression for this thread's 2 anchors ----
    {
        const float4 anv[2] = {an0, an1};
        const bool   val[2] = {v0, v1};
        const int    aix[2] = {A0, A1};
        float flg[2] = {0.0f, 0.0f};
#pragma unroll
        for (int k = 0; k < 2; ++k) {
            if (val[k]) {
                const float aw = anv[k].z - anv[k].x;
                const float ah = anv[k].w - anv[k].y;
                const float iw = fmaxf(fminf(anv[k].z, bx1) - fmaxf(anv[k].x, bx0), 0.0f);
                const float ih = fmaxf(fminf(anv[k].w, by1) - fmaxf(anv[k].y, by0), 0.0f);
                const float inter = iw * ih;
                const float uni = fmaxf(aw * ah + area - inter, 1e-8f);
                const float iou = inter / uni;
                const bool pos = (iou >= 0.5f);
                const bool neg = (iou < 0.4f);
                flg[k] = pos ? 2.0f : (neg ? 1.0f : 0.0f);
                if (pos) {
                    npf += 1.0f;
                    const float acx = anv[k].x + 0.5f * aw;
                    const float acy = anv[k].y + 0.5f * ah;
                    const float t0 = ((gcx - acx) / aw) / 0.1f;
                    const float t1 = ((gcy - acy) / ah) / 0.1f;
                    const float t2 = __logf(gw / aw) / 0.2f;
                    const float t3 = __logf(gh / ah) / 0.2f;
                    const float4 r = *reinterpret_cast<const float4*>(
                        regr + ((size_t)b * A_ANCH + aix[k]) * 4);
                    float d;
                    d = fabsf(t0 - r.x); rl_sum += (d <= TH) ? 4.5f * d * d : d - SUB;
                    d = fabsf(t1 - r.y); rl_sum += (d <= TH) ? 4.5f * d * d : d - SUB;
                    d = fabsf(t2 - r.z); rl_sum += (d <= TH) ? 4.5f * d * d : d - SUB;
                    d = fabsf(t3 - r.w); rl_sum += (d <= TH) ? 4.5f * d * d : d - SUB;
                }
            }
        }
        sF[tid]       = flg[0];
        sF[tid + TPB] = flg[1];
    }
    __syncthreads();

    // ---- Phase B: focal loss over this thread's 20 coalesced floats ----
#pragma unroll
    for (int j = 0; j < 5; ++j) {
        const int l0 = j * (TPB * 4) + tid * 4;          // position-based local index
        const int a0 = (l0 * 6554) >> 16;                // l0 / 10
        const float f0 = sF[a0];
        const float f1 = sF[(a0 < BA - 1) ? a0 + 1 : BA - 1];
        const float pv[4] = {av[j].x, av[j].y, av[j].z, av[j].w};
#pragma unroll
        for (int d = 0; d < 4; ++d) {
            const int l = l0 + d;                        // 0..5119
            const int a = (l * 6554) >> 16;              // l / 10 (exact for l < 16389)
            const int c = l - a * 10;                    // l % 10
            const float flag = (a == a0) ? f0 : f1;
            const float p = fminf(fmaxf(pv[d], 1e-4f), PHI);
            const bool t1 = (flag == 2.0f) && ((labmask >> c) & 1u);
            const float q = 1.0f - p;
            const float x = t1 ? p : q;                  // log argument
            const float w = t1 ? 0.25f * q * q : 0.75f * p * p;
            const float loss = w * (-__logf(x));
            att_sum += (flag != 0.0f) ? loss : 0.0f;
        }
    }

    // wave (64-lane) reduce
#pragma unroll
    for (int off = 32; off > 0; off >>= 1) {
        att_sum += __shfl_down(att_sum, off);
        rl_sum  += __shfl_down(rl_sum, off);
        npf     += __shfl_down(npf, off);
    }

    __shared__ float s_att[TPB / 64];
    __shared__ float s_rl[TPB / 64];
    __shared__ float s_np[TPB / 64];
    const int wave = tid >> 6;
    const int lane = tid & 63;
    if (lane == 0) { s_att[wave] = att_sum; s_rl[wave] = rl_sum; s_np[wave] = npf; }
    __syncthreads();
    if (tid == 0) {
        float a0s = 0.0f, r0 = 0.0f, n0 = 0.0f;
#pragma unroll
        for (int w = 0; w < TPB / 64; ++w) { a0s += s_att[w]; r0 += s_rl[w]; n0 += s_np[w]; }
        const int idx = b * NBX + blk;
        att_part[idx] = a0s;            // plain stores, no atomics
        rl_part[idx]  = r0;
        np_part[idx]  = n0;
    }
}

// One block, 8 waves: wave b tree-reduces image b's NBX partials.
__global__ __launch_bounds__(512) void focal_finalize(
    const float* __restrict__ att_part,
    const float* __restrict__ rl_part,
    const float* __restrict__ np_part,
    float* __restrict__ out)
{
    const int wave = threadIdx.x >> 6;
    const int lane = threadIdx.x & 63;
    float as = 0.0f, rs = 0.0f, ns = 0.0f;
    if (wave < B_IMG) {
        for (int i = lane; i < NBX; i += 64) {
            as += att_part[wave * NBX + i];
            rs += rl_part[wave * NBX + i];
            ns += np_part[wave * NBX + i];
        }
    }
#pragma unroll
    for (int off = 32; off > 0; off >>= 1) {
        as += __shfl_down(as, off);
        rs += __shfl_down(rs, off);
        ns += __shfl_down(ns, off);
    }
    __shared__ float sa[B_IMG], sr[B_IMG], sn[B_IMG];
    if (lane == 0 && wave < B_IMG) { sa[wave] = as; sr[wave] = rs; sn[wave] = ns; }
    __syncthreads();
    if (threadIdx.x == 0) {
        double am = 0.0, rm = 0.0;
        for (int b = 0; b < B_IMG; ++b) {
            const double npd = (double)sn[b];
            const double den = npd > 0.0 ? npd : 1.0;
            am += (double)sa[b] / den;
            if (npd > 0.0) rm += (double)sr[b] / (den * 4.0);
        }
        out[0] = (float)(am / (double)B_IMG);
        out[1] = (float)(rm / (double)B_IMG);
    }
}

extern "C" void kernel_launch(void* const* d_in, const int* in_sizes, int n_in,
                              void* d_out, int out_size, void* d_ws, size_t ws_size,
                              hipStream_t stream) {
    const float* attr = (const float*)d_in[0];   // attributes (B,A,C)
    const float* regr = (const float*)d_in[1];   // regressions (B,A,4)
    const float* anch = (const float*)d_in[2];   // anchors (1,A,4)
    const float* ann  = (const float*)d_in[3];   // annotations (B,14)
    float* out = (float*)d_out;

    float* att_part = (float*)d_ws;
    float* rl_part  = att_part + B_IMG * NBX;
    float* np_part  = rl_part + B_IMG * NBX;
    // All partials are written unconditionally every launch -> no memset needed.

    dim3 grid(NBX, B_IMG);
    focal_main<<<grid, TPB, 0, stream>>>(attr, regr, anch, ann, att_part, rl_part, np_part);
    focal_finalize<<<1, 512, 0, stream>>>(att_part, rl_part, np_part, out);
}

// Round 13
// 23.496 us; speedup vs baseline: 1.1826x; 1.1826x over previous
//
#include <hip/hip_runtime.h>

// Problem constants (match reference)
constexpr int B_IMG = 8;
constexpr int A_ANCH = 150000;
constexpr int C_CLS = 10;
constexpr int TPB = 256;
constexpr int NBX = (A_ANCH + TPB * 2 - 1) / (TPB * 2);   // 293

// ws layout: float att_part[B][NBX], float rl_part[B][NBX], float np_part[B][NBX]
//
// __launch_bounds__(TPB, 8): min 8 waves/EU -> VGPR cap 64 -> full 32 waves/CU
// TLP *and* (via sched_barrier keeping 7 float4 results live) max per-wave
// load ILP. R8 used (TPB,4) which allowed VGPR>64 and silently halved
// occupancy -- confounded test. This is the clean one.
__global__ __launch_bounds__(TPB, 8) void focal_main(
    const float* __restrict__ attr,   // (B, A, C)
    const float* __restrict__ regr,   // (B, A, 4)
    const float* __restrict__ anch,   // (A, 4)
    const float* __restrict__ ann,    // (B, 14)
    float* __restrict__ att_part,
    float* __restrict__ rl_part,
    float* __restrict__ np_part)
{
    const int b = blockIdx.y;
    const int a0 = (blockIdx.x * TPB + threadIdx.x) * 2;
    const bool valid = (a0 < A_ANCH);   // A even, so a0 valid => a0+1 valid

    // ---- issue ALL global loads upfront; sched_barrier pins them before uses ----
    float4 at4[5];   // 2 anchors x 10 classes
    float4 an4[2];   // 2 anchor boxes
    if (valid) {
        const float4* ap = reinterpret_cast<const float4*>(attr + ((size_t)b * A_ANCH + a0) * C_CLS);
#pragma unroll
        for (int j = 0; j < 5; ++j) at4[j] = ap[j];
        const float4* anp = reinterpret_cast<const float4*>(anch) + a0;
        an4[0] = anp[0];
        an4[1] = anp[1];
    }
    __builtin_amdgcn_sched_barrier(0);   // all 7 loads in flight before any consumer

    // annotation is wave-uniform -> scalar loads
    const float* annb = ann + b * 14;
    const float bx0 = annb[0], by0 = annb[1], bx1 = annb[2], by1 = annb[3];
    float lab[C_CLS];
#pragma unroll
    for (int c = 0; c < C_CLS; ++c) lab[c] = annb[4 + c];

    const float gw_raw = bx1 - bx0;
    const float gh_raw = by1 - by0;
    const float area = gw_raw * gh_raw;
    const float gcx = bx0 + 0.5f * gw_raw;
    const float gcy = by0 + 0.5f * gh_raw;
    const float gw = fmaxf(gw_raw, 1.0f);
    const float gh = fmaxf(gh_raw, 1.0f);

    const float TH  = (float)(1.0 / 9.0);
    const float SUB = (float)(0.5 / 9.0);
    const float PHI = (float)(1.0 - 0.0001);

    float att_sum = 0.0f;
    float rl_sum = 0.0f;
    float npf = 0.0f;

    if (valid) {
#pragma unroll
        for (int k = 0; k < 2; ++k) {
            const float ax0 = an4[k].x, ay0 = an4[k].y, ax1 = an4[k].z, ay1 = an4[k].w;
            const float aw = ax1 - ax0;
            const float ah = ay1 - ay0;
            float iw = fminf(ax1, bx1) - fmaxf(ax0, bx0);
            float ih = fminf(ay1, by1) - fmaxf(ay0, by0);
            iw = fmaxf(iw, 0.0f);
            ih = fmaxf(ih, 0.0f);
            const float inter = iw * ih;
            const float uni = fmaxf(aw * ah + area - inter, 1e-8f);
            const float iou = inter / uni;
            const bool pos = (iou >= 0.5f);
            const bool neg = (iou < 0.4f);

            if (pos || neg) {
#pragma unroll
                for (int c = 0; c < C_CLS; ++c) {
                    const int e = k * C_CLS + c;          // element 0..19
                    const float4& v = at4[e >> 2];
                    const float pe = (e & 3) == 0 ? v.x : (e & 3) == 1 ? v.y : (e & 3) == 2 ? v.z : v.w;
                    const float p = fminf(fmaxf(pe, 1e-4f), PHI);
                    const float tgt = pos ? lab[c] : 0.0f;
                    float loss;
                    if (tgt == 1.0f) {
                        const float q = 1.0f - p;
                        loss = 0.25f * (q * q) * (-__logf(p));
                    } else {
                        loss = 0.75f * (p * p) * (-__logf(1.0f - p));
                    }
                    att_sum += loss;
                }
            }
            if (pos) {
                npf += 1.0f;
                const float acx = ax0 + 0.5f * aw;
                const float acy = ay0 + 0.5f * ah;
                const float t0 = ((gcx - acx) / aw) / 0.1f;
                const float t1 = ((gcy - acy) / ah) / 0.1f;
                const float t2 = __logf(gw / aw) / 0.2f;
                const float t3 = __logf(gh / ah) / 0.2f;
                const float4 r = *reinterpret_cast<const float4*>(regr + ((size_t)b * A_ANCH + a0 + k) * 4);
                float d;
                d = fabsf(t0 - r.x); rl_sum += (d <= TH) ? 4.5f * d * d : d - SUB;
                d = fabsf(t1 - r.y); rl_sum += (d <= TH) ? 4.5f * d * d : d - SUB;
                d = fabsf(t2 - r.z); rl_sum += (d <= TH) ? 4.5f * d * d : d - SUB;
                d = fabsf(t3 - r.w); rl_sum += (d <= TH) ? 4.5f * d * d : d - SUB;
            }
        }
    }

    // wave (64-lane) reduce
#pragma unroll
    for (int off = 32; off > 0; off >>= 1) {
        att_sum += __shfl_down(att_sum, off);
        rl_sum  += __shfl_down(rl_sum, off);
        npf     += __shfl_down(npf, off);
    }

    __shared__ float s_att[TPB / 64];
    __shared__ float s_rl[TPB / 64];
    __shared__ float s_np[TPB / 64];
    const int wave = threadIdx.x >> 6;
    const int lane = threadIdx.x & 63;
    if (lane == 0) { s_att[wave] = att_sum; s_rl[wave] = rl_sum; s_np[wave] = npf; }
    __syncthreads();
    if (threadIdx.x == 0) {
        float a0s = 0.0f, r0 = 0.0f, n0 = 0.0f;
#pragma unroll
        for (int w = 0; w < TPB / 64; ++w) { a0s += s_att[w]; r0 += s_rl[w]; n0 += s_np[w]; }
        const int idx = b * NBX + blockIdx.x;
        att_part[idx] = a0s;            // plain stores, no atomics
        rl_part[idx]  = r0;
        np_part[idx]  = n0;             // counts < 2^24, exact in float
    }
}

// One block, 8 waves: wave b tree-reduces image b's NBX partials.
__global__ __launch_bounds__(512) void focal_finalize(
    const float* __restrict__ att_part,
    const float* __restrict__ rl_part,
    const float* __restrict__ np_part,
    float* __restrict__ out)
{
    const int wave = threadIdx.x >> 6;
    const int lane = threadIdx.x & 63;
    float as = 0.0f, rs = 0.0f, ns = 0.0f;
    if (wave < B_IMG) {
        for (int i = lane; i < NBX; i += 64) {
            as += att_part[wave * NBX + i];
            rs += rl_part[wave * NBX + i];
            ns += np_part[wave * NBX + i];
        }
    }
#pragma unroll
    for (int off = 32; off > 0; off >>= 1) {
        as += __shfl_down(as, off);
        rs += __shfl_down(rs, off);
        ns += __shfl_down(ns, off);
    }
    __shared__ float sa[B_IMG], sr[B_IMG], sn[B_IMG];
    if (lane == 0 && wave < B_IMG) { sa[wave] = as; sr[wave] = rs; sn[wave] = ns; }
    __syncthreads();
    if (threadIdx.x == 0) {
        double am = 0.0, rm = 0.0;
        for (int b = 0; b < B_IMG; ++b) {
            const double npd = (double)sn[b];
            const double npf = npd > 0.0 ? npd : 1.0;
            am += (double)sa[b] / npf;
            if (npd > 0.0) rm += (double)sr[b] / (npf * 4.0);
        }
        out[0] = (float)(am / (double)B_IMG);
        out[1] = (float)(rm / (double)B_IMG);
    }
}

extern "C" void kernel_launch(void* const* d_in, const int* in_sizes, int n_in,
                              void* d_out, int out_size, void* d_ws, size_t ws_size,
                              hipStream_t stream) {
    const float* attr = (const float*)d_in[0];   // attributes (B,A,C)
    const float* regr = (const float*)d_in[1];   // regressions (B,A,4)
    const float* anch = (const float*)d_in[2];   // anchors (1,A,4)
    const float* ann  = (const float*)d_in[3];   // annotations (B,14)
    float* out = (float*)d_out;

    float* att_part = (float*)d_ws;
    float* rl_part  = att_part + B_IMG * NBX;
    float* np_part  = rl_part + B_IMG * NBX;
    // All partials are stored unconditionally every launch -> no memset needed.

    dim3 grid(NBX, B_IMG);
    focal_main<<<grid, TPB, 0, stream>>>(attr, regr, anch, ann, att_part, rl_part, np_part);
    focal_finalize<<<1, 512, 0, stream>>>(att_part, rl_part, np_part, out);
}